// Round 3
// baseline (375.322 us; speedup 1.0000x reference)
//
#include <hip/hip_runtime.h>
#include <math.h>

#define NF 8
#define SS 5
#define DIN 64
#define KSTEP 3
#define BT 32
#define FH_PAD 68            // fS row pad (LDS bank spread)
#define FH_STR (SS*DIN)      // 320, unpadded fh row stride in ws (global)
#define HOPSTR (NF*FH_STR)   // 2560
#define NS_OFF (KSTEP*HOPSTR) // 7680: nsqh [3][8][5]

// exp(-(sqf+sqh-2cr)/3.2) = 2^(CC*cr - CS*sqf - CS*sqh)
#define CS 0.45084219902780109f
#define CC 0.90168439805560218f

__device__ __forceinline__ float fexp2(float x) {
#if __has_builtin(__builtin_amdgcn_exp2f)
  return __builtin_amdgcn_exp2f(x);
#else
  return exp2f(x);
#endif
}

__global__ __launch_bounds__(256) void hidden_prep(
    const float* __restrict__ adjs_hidden,
    const float* __restrict__ features_hidden,
    float* __restrict__ ws)
{
  __shared__ float Ah[NF][SS][SS];
  __shared__ float buf[2][NF][SS][DIN];
  const int t = threadIdx.x;

  if (t < NF*SS*SS) ((float*)Ah)[t] = 0.0f;
  for (int i = t; i < NF*SS*DIN; i += 256) ((float*)buf[0])[i] = features_hidden[i];
  __syncthreads();
  if (t < NF*10) {
    const int iu0[10] = {0,0,0,0,1,1,1,2,2,3};
    const int iu1[10] = {1,2,3,4,2,3,4,3,4,4};
    int f = t / 10, k = t % 10;
    float sg = 1.0f / (1.0f + expf(-adjs_hidden[t]));
    Ah[f][iu0[k]][iu1[k]] = sg;
    Ah[f][iu1[k]][iu0[k]] = sg;
  }
  __syncthreads();

  int cur = 0;
  for (int h = 0; h < KSTEP; ++h) {
    // write unpadded fh for this hop: ws[h][f][s][d]
    for (int i = t; i < NF*SS*DIN; i += 256)
      ws[h*HOPSTR + i] = ((float*)buf[cur])[i];
    // negated, pre-scaled sq_h
    if (t < NF*SS) {
      float acc = 0.0f;
      int f = t / SS, s = t % SS;
      for (int d = 0; d < DIN; ++d) { float v = buf[cur][f][s][d]; acc = fmaf(v, v, acc); }
      ws[NS_OFF + h*NF*SS + t] = -acc * CS;
    }
    if (h + 1 < KSTEP) {
      __syncthreads();
      for (int i = t; i < NF*SS*DIN; i += 256) {
        int f = i / (SS*DIN), s = (i / DIN) % SS, d = i % DIN;
        float acc = 0.0f;
        for (int j = 0; j < SS; ++j) acc = fmaf(Ah[f][s][j], buf[cur][f][j][d], acc);
        buf[cur^1][f][s][d] = acc;
      }
      __syncthreads();
      cur ^= 1;
    }
  }
}

// Barrier-free main kernel: all cross-thread LDS deps are octet-local
// (8 consecutive lanes share one b), so wave-lockstep + lgkmcnt ordering
// suffices. fh/nsqh are read from global (ws) - 30.7 KB, L1-resident.
__global__ __launch_bounds__(256) void kc_main(
    const float* __restrict__ adjs,
    const float* __restrict__ feature,
    const int* __restrict__ idxs,
    const float* __restrict__ ws,
    float* __restrict__ out,
    int B, int N)
{
  __shared__ float fS[BT][SS][FH_PAD];   // 43520 B
  __shared__ float adjS[BT][28];         // 3584 B
  __shared__ float sqfS[BT][8];          // 1024 B
                                         // total ~48 KB -> 3 blocks/CU

  const int t   = threadIdx.x;
  const int b_i = t >> 3;   // 0..31  (octet id within block)
  const int f_  = t & 7;    // 0..7   (filter / d-slice owner)
  const int bg  = blockIdx.x * BT + b_i;
  const bool valid = bg < B;

  // --- stage adj (octet-local, coalesced: lanes k=f_+8j) ---
  #pragma unroll
  for (int k = f_; k < SS*SS; k += 8)
    adjS[b_i][k] = valid ? adjs[(size_t)bg*(SS*SS) + k] : 0.0f;

  // --- gather f rows: thread owns d-columns [8f_, 8f_+8) ---
  int idxv[SS];
  #pragma unroll
  for (int m = 0; m < SS; ++m)
    idxv[m] = valid ? idxs[bg*SS + m] : -1;
  #pragma unroll
  for (int m = 0; m < SS; ++m) {
    #pragma unroll
    for (int h2 = 0; h2 < 2; ++h2) {
      float4 v = make_float4(0.f, 0.f, 0.f, 0.f);
      if ((unsigned)idxv[m] < (unsigned)N)
        v = reinterpret_cast<const float4*>(feature)[(size_t)idxv[m]*16 + f_*2 + h2];
      *reinterpret_cast<float4*>(&fS[b_i][m][f_*8 + h2*4]) = v;
    }
  }
  // (no barrier: consumed only by this octet, same wave)

  float total[SS][SS];
  #pragma unroll
  for (int m = 0; m < SS; ++m)
    #pragma unroll
    for (int s = 0; s < SS; ++s) total[m][s] = 0.0f;

  #pragma unroll 1
  for (int hop = 0; hop < KSTEP; ++hop) {
    if (hop) {
      // f <- adjs @ f : thread-local (reads+writes only its own d-columns)
      const int dbase = f_ * 8;
      float a[SS][SS];
      #pragma unroll
      for (int m = 0; m < SS; ++m)
        #pragma unroll
        for (int j = 0; j < SS; ++j) a[m][j] = adjS[b_i][m*SS + j];
      float fo[SS][8];
      #pragma unroll
      for (int j = 0; j < SS; ++j)
        #pragma unroll
        for (int h2 = 0; h2 < 2; ++h2) {
          float4 v = *reinterpret_cast<const float4*>(&fS[b_i][j][dbase + h2*4]);
          fo[j][h2*4+0] = v.x; fo[j][h2*4+1] = v.y; fo[j][h2*4+2] = v.z; fo[j][h2*4+3] = v.w;
        }
      #pragma unroll
      for (int m = 0; m < SS; ++m) {
        float fn[8];
        #pragma unroll
        for (int dd = 0; dd < 8; ++dd) fn[dd] = 0.0f;
        #pragma unroll
        for (int j = 0; j < SS; ++j)
          #pragma unroll
          for (int dd = 0; dd < 8; ++dd) fn[dd] = fmaf(a[m][j], fo[j][dd], fn[dd]);
        #pragma unroll
        for (int h2 = 0; h2 < 2; ++h2) {
          float4 v = make_float4(fn[h2*4+0], fn[h2*4+1], fn[h2*4+2], fn[h2*4+3]);
          *reinterpret_cast<float4*>(&fS[b_i][m][dbase + h2*4]) = v;
        }
      }
      // (no barrier: octet-local, same wave)
    }

    // shared ||f||^2 (pre-scaled by CS): lanes f_<5 do one row each
    if (f_ < SS) {
      float acc = 0.0f;
      const float* fr = &fS[b_i][f_][0];
      #pragma unroll
      for (int d4 = 0; d4 < 16; ++d4) {
        float4 v = *reinterpret_cast<const float4*>(&fr[d4*4]);
        acc = fmaf(v.x, v.x, acc);
        acc = fmaf(v.y, v.y, acc);
        acc = fmaf(v.z, v.z, acc);
        acc = fmaf(v.w, v.w, acc);
      }
      sqfS[b_i][f_] = acc * CS;
    }
    // (no barrier: octet-local, same wave)

    float cr[SS][SS];
    #pragma unroll
    for (int m = 0; m < SS; ++m)
      #pragma unroll
      for (int s = 0; s < SS; ++s) cr[m][s] = 0.0f;

    const float4* hv4 = reinterpret_cast<const float4*>(ws + hop*HOPSTR + f_*FH_STR);
    #pragma unroll
    for (int d4 = 0; d4 < 16; ++d4) {
      float4 fv[SS], hv[SS];
      #pragma unroll
      for (int m = 0; m < SS; ++m)
        fv[m] = *reinterpret_cast<const float4*>(&fS[b_i][m][d4*4]);
      #pragma unroll
      for (int s = 0; s < SS; ++s)
        hv[s] = hv4[s*16 + d4];   // global, L1-hot, base+imm offsets
      #pragma unroll
      for (int m = 0; m < SS; ++m)
        #pragma unroll
        for (int s = 0; s < SS; ++s) {
          cr[m][s] = fmaf(fv[m].x, hv[s].x, cr[m][s]);
          cr[m][s] = fmaf(fv[m].y, hv[s].y, cr[m][s]);
          cr[m][s] = fmaf(fv[m].z, hv[s].z, cr[m][s]);
          cr[m][s] = fmaf(fv[m].w, hv[s].w, cr[m][s]);
        }
    }

    float sqf2[SS], nh[SS];
    #pragma unroll
    for (int m = 0; m < SS; ++m) sqf2[m] = sqfS[b_i][m];
    const float* nsq = ws + NS_OFF + hop*NF*SS + f_*SS;
    #pragma unroll
    for (int s = 0; s < SS; ++s) nh[s] = nsq[s];
    #pragma unroll
    for (int m = 0; m < SS; ++m)
      #pragma unroll
      for (int s = 0; s < SS; ++s) {
        float arg = fmaf(CC, cr[m][s], nh[s] - sqf2[m]);  // <= 0 always
        total[m][s] += fexp2(arg);
      }
  }

  // greedy matching: row 0 -> col 0; rows 1..4 argmax over untaken cols
  float res = total[0][0];
  int taken = 1;
  #pragma unroll
  for (int r = 1; r < SS; ++r) {
    float best = -2.0f; int bi = 0;
    #pragma unroll
    for (int s = 0; s < SS; ++s) {
      float sc = ((taken >> s) & 1) ? -1.0f : total[r][s];
      if (sc > best) { best = sc; bi = s; }
    }
    res += best;
    taken |= (1 << bi);
  }
  if (valid) out[(size_t)bg*NF + f_] = res;
}

extern "C" void kernel_launch(void* const* d_in, const int* in_sizes, int n_in,
                              void* d_out, int out_size, void* d_ws, size_t ws_size,
                              hipStream_t stream) {
  const float* adjs            = (const float*)d_in[0];
  const float* feature         = (const float*)d_in[1];
  const int*   idxs            = (const int*)d_in[2];
  const float* adjs_hidden     = (const float*)d_in[3];
  const float* features_hidden = (const float*)d_in[4];
  float* out = (float*)d_out;
  float* ws  = (float*)d_ws;

  const int B = in_sizes[0] / (SS*SS);
  const int N = in_sizes[1] / DIN;

  hipLaunchKernelGGL(hidden_prep, dim3(1), dim3(256), 0, stream,
                     adjs_hidden, features_hidden, ws);
  const int nblk = (B + BT - 1) / BT;
  hipLaunchKernelGGL(kc_main, dim3(nblk), dim3(256), 0, stream,
                     adjs, feature, idxs, ws, out, B, N);
}